// Round 5
// baseline (6843.641 us; speedup 1.0000x reference)
//
#include <hip/hip_runtime.h>
#include <math.h>
#include <stdint.h>

// Problem dims
#define NB 16384    // batch
#define NH 768      // hidden
#define ND 784      // input features
#define NC 10       // classes
#define NW 12       // u64 words per 768-bit row

// gemm1 tiling
#define XP 788      // xs row pitch (f32): 3152 B = 197 quads (odd) -> conflict-free
#define WPB 408     // wl col pitch (bf16): 816 B = 204 words, 204%32=12 -> 12c mod 32
                    // spans all 8 bank-quads over 8 consecutive lanes -> conflict-free

// ---------------------------------------------------------------------------
// prep: BN params in FAITHFUL f32 (replicating np op-by-op):
// sc = g * (1 / sqrt(v + 1e-5)), each op f32-rounded. [0]=sc,[1]=m,[2]=be,[3]=bias
// ---------------------------------------------------------------------------
__global__ void k_bnprep_f32(const float* __restrict__ g, const float* __restrict__ be,
                             const float* __restrict__ m, const float* __restrict__ v,
                             const float* __restrict__ bias, float* __restrict__ out) {
    int i = blockIdx.x * 256 + threadIdx.x;
    if (i >= NH) return;
    float t1 = __fadd_rn(v[i], 1e-5f);
    float t2 = __fsqrt_rn(t1);
    float t3 = __fdiv_rn(1.0f, t2);
    out[i]          = __fmul_rn(g[i], t3);
    out[NH + i]     = m[i];
    out[2 * NH + i] = be[i];
    out[3 * NH + i] = bias[i];
}

// ---------------------------------------------------------------------------
// prep: W1 signs as bf16 +/-1 bit patterns (0x3F80 / 0xBF80), row-major [col][k]
// ---------------------------------------------------------------------------
__global__ void k_pack_w1bf(const float* __restrict__ W1, unsigned short* __restrict__ wbf) {
    int k = blockIdx.x * 256 + threadIdx.x;
    int col = blockIdx.y;
    if (k >= ND) return;
    float v = W1[(size_t)col * ND + k];
    wbf[(size_t)col * ND + k] = (v >= 0.0f) ? (unsigned short)0x3F80 : (unsigned short)0xBF80;
}

// ---------------------------------------------------------------------------
// prep: W2/W3 sign bits, transposed words: wT[j*768 + col] bit l = (W[col][j*64+l] >= 0)
// ---------------------------------------------------------------------------
__global__ void k_pack_wT(const float* __restrict__ W, unsigned long long* __restrict__ wT) {
    int idx = blockIdx.x * 256 + threadIdx.x;
    if (idx >= NH * NW) return;
    int col = idx / NW, j = idx % NW;
    unsigned long long w = 0ull;
    for (int l = 0; l < 64; ++l) {
        float v = W[(size_t)col * NH + j * 64 + l];
        w |= (unsigned long long)(v >= 0.0f ? 1 : 0) << l;
    }
    wT[(size_t)j * NH + col] = w;
}

// ---------------------------------------------------------------------------
// GEMM1 replicating numpy einsum sum_of_products_contig_two (AVX512 npyv).
// Chain structure IDENTICAL to the 706us R9 kernel (bit-exact s1 output):
//   per (row,col): a[g][i] accumulates k = t*64 + g*16 + (jh*8+i), t = 0..11
//   ascending, tail k=768.. into group 0; combine (a0+a1)+(a2+a3); pair-sum
//   via shfl_xor(32); tree 8/4/2/1; BN f32 op-by-op; ballot -> sign bits.
// R14 = R13 with the w-staging count bug fixed (R13 post-mortem: each k-half
// needs 48|50 uint4 PER COLUMN — 384|400 bf16 — but staged only 24|25, so
// the compute loop read un-staged LDS -> absmax 8.8. Counts now match R11's
// verified per-column staging).
// Structure vs R9 (math identical; R9 LDS GEOMETRY preserved exactly):
//   - wave = (rp, ch): rows {2rp, 2rp+1}, cols cb + ch*32 + colsub.
//     TWO rows per wave: w-frag read+unpacked ONCE per 16 MACs (was per 8)
//     -> VALU/MAC ~1.6 (was 2.25) and w-LDS bytes/MAC 1 (was 2).
//   - w-read geometry = R9's proven-conflict-free: uint4 from row colsub
//     (+ch*32), pitch 204 words. x-reads wave-uniform broadcast.
//     [R12 post-mortem: lane-remap broke this -> 7.5e7 conflicts.]
//   - 64 accs as named arrays a0[4][8], a1[4][8], static indices only
//     (R11 post-mortem: pointer-select -> SROA failure -> scratch).
//   - __launch_bounds__(512,2) = CUDA min-BLOCKS semantics (measured:
//     (512,4)->cap 64 twice, (512,2)->cap 128): cap 128 >= ~100 live.
//   - W staged bf16 for all 64 cols in two k-halves (t=0..5 | 6..11+tail,
//     ascending -> chain order unchanged). LDS 77,440 B -> 2 blocks/CU.
// Block: 512 thr = 8 waves; grid (NB/8, NH/64).
// ---------------------------------------------------------------------------
#define UNPACK_W(wA)                                                   \
    {                                                                  \
        unsigned int dw[4] = {wA.x, wA.y, wA.z, wA.w};                 \
        _Pragma("unroll")                                              \
        for (int p = 0; p < 4; ++p) {                                  \
            wf[2 * p]     = __uint_as_float(dw[p] << 16);              \
            wf[2 * p + 1] = __uint_as_float(dw[p] & 0xFFFF0000u);      \
        }                                                              \
    }

#define FMA8G(A, G, X0, X1)                                            \
    {                                                                  \
        float xv[8] = {X0.x, X0.y, X0.z, X0.w, X1.x, X1.y, X1.z, X1.w};\
        _Pragma("unroll")                                              \
        for (int i = 0; i < 8; ++i)                                    \
            A[G][i] = __fmaf_rn(wf[i], xv[i], A[G][i]);                \
    }

// combine + epilogue for one row; A = acc array NAME (static, no pointers)
#define COMB_EPI(A, RIDX)                                                    \
    {                                                                        \
        float v[8];                                                          \
        _Pragma("unroll")                                                    \
        for (int i = 0; i < 8; ++i)                                          \
            v[i] = __fadd_rn(__fadd_rn(A[0][i], A[1][i]),                    \
                             __fadd_rn(A[2][i], A[3][i]));                   \
        float h8[8];                                                         \
        _Pragma("unroll")                                                    \
        for (int i = 0; i < 8; ++i) {                                        \
            float o = __shfl_xor(v[i], 32, 64);                              \
            h8[i] = __fadd_rn(v[i], o);                                      \
        }                                                                    \
        float h4[4], h2[2];                                                  \
        _Pragma("unroll")                                                    \
        for (int i = 0; i < 4; ++i) h4[i] = __fadd_rn(h8[i], h8[i + 4]);     \
        _Pragma("unroll")                                                    \
        for (int i = 0; i < 2; ++i) h2[i] = __fadd_rn(h4[i], h4[i + 2]);     \
        float acc = __fadd_rn(h2[0], h2[1]);                                 \
        float h  = __fadd_rn(acc, bias);                                     \
        float t1 = __fsub_rn(h, mm);                                         \
        float u  = __fmul_rn(t1, sc);                                        \
        float hb = __fadd_rn(u, be);                                         \
        unsigned long long word = __ballot(hb >= 0.0f);                      \
        if (lane == 0)                                                       \
            s1p32[(size_t)(r0 + rA + (RIDX)) * (2 * NW) + blockIdx.y * 2 + ch] = \
                (unsigned int)word;                                          \
    }

__global__ __launch_bounds__(512, 2)
void k_gemm1_p2(const float* __restrict__ x, const unsigned short* __restrict__ wbf,
                const float* __restrict__ bnp, unsigned int* __restrict__ s1p32) {
    __shared__ alignas(16) float xs[8][XP];              // 25,216 B
    __shared__ alignas(16) unsigned short wl[64][WPB];   // 52,224 B

    const int tid = threadIdx.x;
    const int wave = tid >> 6, lane = tid & 63;
    const int colsub = lane & 31, jh = lane >> 5;
    const int j0 = jh * 8;
    const int rp = wave >> 1, ch = wave & 1;
    const int rA = 2 * rp;
    const int r0 = blockIdx.x * 8;
    const int cb = blockIdx.y * 64;

    // stage x: wave w stages block-row w (196 float4, lane-strided; reads occur
    // only after the first __syncthreads below)
    {
        const float4* src = (const float4*)(x + (size_t)(r0 + wave) * ND);
        float4* dst = (float4*)&xs[wave][0];
        for (int k4 = lane; k4 < ND / 4; k4 += 64) dst[k4] = src[k4];
    }

    float a0[4][8], a1[4][8];
#pragma unroll
    for (int g = 0; g < 4; ++g)
#pragma unroll
        for (int i = 0; i < 8; ++i) { a0[g][i] = 0.0f; a1[g][i] = 0.0f; }

    const float* xr0 = &xs[rA][j0];
    const float* xr1 = &xs[rA + 1][j0];
    const unsigned short* wrow = &wl[ch * 32 + colsub][j0];

#pragma unroll 1
    for (int half = 0; half < 2; ++half) {
        __syncthreads();   // half0: orders x-stage; half1: all waves done with wl half0
        // stage w half: 64 cols x (48|50) uint4 of bf16 signs; 8 threads/col
        // (48 uint4 = 384 bf16 = the 6 t-supertiles of this half; half1 +tail)
        {
            const int c = tid >> 3, q0 = tid & 7;
            const int nq = (half == 0) ? 48 : 50;    // half1: k 384..783 (400 bf16)
            uint4* dst = (uint4*)&wl[c][0];
            const uint4* src = (const uint4*)(wbf + (size_t)(cb + c) * ND) + half * 48;
            for (int q = q0; q < nq; q += 8) dst[q] = src[q];
        }
        __syncthreads();

        const int kb = half * 384;      // global k base of this half
#pragma unroll
        for (int t = 0; t < 6; ++t) {   // global t = half*6 + t, ascending
#pragma unroll
            for (int g = 0; g < 4; ++g) {
                const int kk = t * 64 + g * 16;       // k offset within half
                uint4 wA = *(const uint4*)(wrow + kk);
                float wf[8];
                UNPACK_W(wA);
                float4 x0 = *(const float4*)(xr0 + kb + kk);
                float4 x1 = *(const float4*)(xr0 + kb + kk + 4);
                FMA8G(a0, g, x0, x1);
                float4 y0 = *(const float4*)(xr1 + kb + kk);
                float4 y1 = *(const float4*)(xr1 + kb + kk + 4);
                FMA8G(a1, g, y0, y1);
            }
        }
        if (half == 1) {
            // tail k = 768..783 (local 384..399) into group 0, after t=11
            uint4 wA = *(const uint4*)(wrow + 384);
            float wf[8];
            UNPACK_W(wA);
            float4 x0 = *(const float4*)(xr0 + 768);
            float4 x1 = *(const float4*)(xr0 + 768 + 4);
            FMA8G(a0, 0, x0, x1);
            float4 y0 = *(const float4*)(xr1 + 768);
            float4 y1 = *(const float4*)(xr1 + 768 + 4);
            FMA8G(a1, 0, y0, y1);
        }
    }

    // -------- combine + epilogue (exact R9 op sequence, per row) --------
    const int col = cb + ch * 32 + colsub;
    const float sc = bnp[col], mm = bnp[NH + col], be = bnp[2 * NH + col],
                bias = bnp[3 * NH + col];

    COMB_EPI(a0, 0)
    COMB_EPI(a1, 1)
}

// ---------------------------------------------------------------------------
// Binary layers 2/3: dot = 768 - 2*popcount(a XOR w) — exact integer, matches
// any-order f32 evaluation of +/-1 GEMM bit-for-bit (all partials exact).
// Epilogue faithful f32: h = fl(dot + b), BN op-by-op.
// MODE 0: sign -> packed bits. MODE 1: hardtanh -> f32 out.
// ---------------------------------------------------------------------------
template <int MODE>
__global__ __launch_bounds__(256, 2)
void k_popbin(const unsigned long long* __restrict__ Ap,
              const unsigned long long* __restrict__ wT,
              const float* __restrict__ bnp,
              unsigned long long* __restrict__ Sp, float* __restrict__ h_out) {
    __shared__ unsigned long long as[64][NW];
    const int tid = threadIdx.x;
    const int b0 = blockIdx.x * 64;

    {
        unsigned long long* asf = &as[0][0];
        const unsigned long long* src = Ap + (size_t)b0 * NW;
        for (int i = tid; i < 64 * NW; i += 256) asf[i] = src[i];
    }
    __syncthreads();

    const int wave = tid >> 6, lane = tid & 63;

    for (int chunk = 0; chunk < NW; ++chunk) {
        const int col = chunk * 64 + lane;
        unsigned long long w[NW];
#pragma unroll
        for (int j = 0; j < NW; ++j) w[j] = wT[(size_t)j * NH + col];
        const float sc = bnp[col], mm = bnp[NH + col], be = bnp[2 * NH + col],
                    bias = bnp[3 * NH + col];
        for (int r = 0; r < 16; ++r) {
            const int row = wave * 16 + r;
            int d = 0;
#pragma unroll
            for (int j = 0; j < NW; ++j)
                d += __builtin_popcountll(as[row][j] ^ w[j]);
            int dot = NH - 2 * d;
            float h  = __fadd_rn((float)dot, bias);
            float t  = __fsub_rn(h, mm);
            float u  = __fmul_rn(t, sc);
            float hb = __fadd_rn(u, be);
            if (MODE == 0) {
                unsigned long long word = __ballot(hb >= 0.0f);
                if (lane == 0) Sp[(size_t)(b0 + row) * NW + chunk] = word;
            } else {
                float hc = fminf(fmaxf(hb, -1.0f), 1.0f);
                h_out[(size_t)(b0 + row) * NH + col] = hc;
            }
        }
    }
}

// ---------------------------------------------------------------------------
// fc4 + log_softmax: one wave per row, double accumulation + shuffle reduce
// ---------------------------------------------------------------------------
__global__ __launch_bounds__(256, 4)
void k_fc4(const float* __restrict__ h3, const float* __restrict__ W4,
           const float* __restrict__ b4, float* __restrict__ out) {
    __shared__ float w4s[NC * NH];
    const int tid = threadIdx.x;
    for (int i = tid; i < NC * NH; i += 256) w4s[i] = W4[i];
    __syncthreads();

    const int wave = tid >> 6, lane = tid & 63;
    const int row = blockIdx.x * 4 + wave;
    const float* hrow = h3 + (size_t)row * NH;

    double p[NC];
#pragma unroll
    for (int c = 0; c < NC; ++c) p[c] = 0.0;

    for (int it = 0; it < NH / 64; ++it) {
        int j = it * 64 + lane;
        double hv = (double)hrow[j];
#pragma unroll
        for (int c = 0; c < NC; ++c) p[c] += hv * (double)w4s[c * NH + j];
    }
#pragma unroll
    for (int c = 0; c < NC; ++c) {
#pragma unroll
        for (int off = 32; off > 0; off >>= 1) p[c] += __shfl_xor(p[c], off, 64);
    }
    double lg[NC];
    double mx = -1e300;
#pragma unroll
    for (int c = 0; c < NC; ++c) {
        lg[c] = p[c] + (double)b4[c];
        mx = fmax(mx, lg[c]);
    }
    double s = 0.0;
#pragma unroll
    for (int c = 0; c < NC; ++c) s += exp(lg[c] - mx);
    double lse = mx + log(s);
    if (lane < NC) {
        double v = 0.0;
#pragma unroll
        for (int c = 0; c < NC; ++c)
            if (lane == c) v = lg[c];
        out[(size_t)row * NC + lane] = (float)(v - lse);
    }
}

// ---------------------------------------------------------------------------
// launch
// ---------------------------------------------------------------------------
extern "C" void kernel_launch(void* const* d_in, const int* in_sizes, int n_in,
                              void* d_out, int out_size, void* d_ws, size_t ws_size,
                              hipStream_t stream) {
    const float* x  = (const float*)d_in[0];
    const float* W1 = (const float*)d_in[1];
    const float* b1 = (const float*)d_in[2];
    const float* W2 = (const float*)d_in[3];
    const float* b2 = (const float*)d_in[4];
    const float* W3 = (const float*)d_in[5];
    const float* b3 = (const float*)d_in[6];
    const float* W4 = (const float*)d_in[7];
    const float* b4 = (const float*)d_in[8];
    const float* g1 = (const float*)d_in[9],  *be1 = (const float*)d_in[10];
    const float* m1 = (const float*)d_in[11], *v1  = (const float*)d_in[12];
    const float* g2 = (const float*)d_in[13], *be2 = (const float*)d_in[14];
    const float* m2 = (const float*)d_in[15], *v2  = (const float*)d_in[16];
    const float* g3 = (const float*)d_in[17], *be3 = (const float*)d_in[18];
    const float* m3 = (const float*)d_in[19], *v3  = (const float*)d_in[20];
    float* out = (float*)d_out;

    char* ws = (char*)d_ws;
    size_t off = 0;
    unsigned short* wbf = (unsigned short*)(ws + off);  off += (size_t)NH * ND * 2;
    unsigned long long* w2pT = (unsigned long long*)(ws + off); off += (size_t)NW * NH * 8;
    unsigned long long* w3pT = (unsigned long long*)(ws + off); off += (size_t)NW * NH * 8;
    unsigned long long* s1p  = (unsigned long long*)(ws + off); off += (size_t)NB * NW * 8;
    unsigned long long* s2p  = (unsigned long long*)(ws + off); off += (size_t)NB * NW * 8;
    float*  h3   = (float*)(ws + off);              off += (size_t)NB * NH * 4;
    float* bnp1 = (float*)(ws + off);               off += (size_t)4 * NH * 4;
    float* bnp2 = (float*)(ws + off);               off += (size_t)4 * NH * 4;
    float* bnp3 = (float*)(ws + off);               off += (size_t)4 * NH * 4;
    (void)ws_size; (void)in_sizes; (void)n_in; (void)out_size;

    // prep
    k_pack_w1bf<<<dim3(4, NH), 256, 0, stream>>>(W1, wbf);
    k_pack_wT<<<dim3((NH * NW + 255) / 256), 256, 0, stream>>>(W2, w2pT);
    k_pack_wT<<<dim3((NH * NW + 255) / 256), 256, 0, stream>>>(W3, w3pT);
    k_bnprep_f32<<<dim3(3), 256, 0, stream>>>(g1, be1, m1, v1, b1, bnp1);
    k_bnprep_f32<<<dim3(3), 256, 0, stream>>>(g2, be2, m2, v2, b2, bnp2);
    k_bnprep_f32<<<dim3(3), 256, 0, stream>>>(g3, be3, m3, v3, b3, bnp3);

    // layers
    k_gemm1_p2<<<dim3(NB / 8, NH / 64), 512, 0, stream>>>(x, wbf, bnp1,
                                                          (unsigned int*)s1p);
    k_popbin<0><<<dim3(NB / 64), 256, 0, stream>>>(s1p, w2pT, bnp2, s2p, nullptr);
    k_popbin<1><<<dim3(NB / 64), 256, 0, stream>>>(s2p, w3pT, bnp3, nullptr, h3);
    k_fc4<<<dim3(NB / 4), 256, 0, stream>>>(h3, W4, b4, out);
}

// Round 6
// 1037.800 us; speedup vs baseline: 6.5944x; 6.5944x over previous
//
#include <hip/hip_runtime.h>
#include <math.h>
#include <stdint.h>

// Problem dims
#define NB 16384    // batch
#define NH 768      // hidden
#define ND 784      // input features
#define NC 10       // classes
#define NW 12       // u64 words per 768-bit row

// gemm1 tiling
#define XP 788      // xs row pitch (f32): 3152 B = 197 quads (odd) -> conflict-free
#define WPB 408     // wl col pitch (bf16): 816 B = 204 words, 204%32=12 -> 12c mod 32
                    // spans all 8 bank-quads over 8 consecutive lanes -> conflict-free

// ---------------------------------------------------------------------------
// prep: BN params in FAITHFUL f32 (replicating np op-by-op):
// sc = g * (1 / sqrt(v + 1e-5)), each op f32-rounded. [0]=sc,[1]=m,[2]=be,[3]=bias
// ---------------------------------------------------------------------------
__global__ void k_bnprep_f32(const float* __restrict__ g, const float* __restrict__ be,
                             const float* __restrict__ m, const float* __restrict__ v,
                             const float* __restrict__ bias, float* __restrict__ out) {
    int i = blockIdx.x * 256 + threadIdx.x;
    if (i >= NH) return;
    float t1 = __fadd_rn(v[i], 1e-5f);
    float t2 = __fsqrt_rn(t1);
    float t3 = __fdiv_rn(1.0f, t2);
    out[i]          = __fmul_rn(g[i], t3);
    out[NH + i]     = m[i];
    out[2 * NH + i] = be[i];
    out[3 * NH + i] = bias[i];
}

// ---------------------------------------------------------------------------
// prep: W1 signs as bf16 +/-1 bit patterns (0x3F80 / 0xBF80), row-major [col][k]
// ---------------------------------------------------------------------------
__global__ void k_pack_w1bf(const float* __restrict__ W1, unsigned short* __restrict__ wbf) {
    int k = blockIdx.x * 256 + threadIdx.x;
    int col = blockIdx.y;
    if (k >= ND) return;
    float v = W1[(size_t)col * ND + k];
    wbf[(size_t)col * ND + k] = (v >= 0.0f) ? (unsigned short)0x3F80 : (unsigned short)0xBF80;
}

// ---------------------------------------------------------------------------
// prep: W2/W3 sign bits, transposed words: wT[j*768 + col] bit l = (W[col][j*64+l] >= 0)
// ---------------------------------------------------------------------------
__global__ void k_pack_wT(const float* __restrict__ W, unsigned long long* __restrict__ wT) {
    int idx = blockIdx.x * 256 + threadIdx.x;
    if (idx >= NH * NW) return;
    int col = idx / NW, j = idx % NW;
    unsigned long long w = 0ull;
    for (int l = 0; l < 64; ++l) {
        float v = W[(size_t)col * NH + j * 64 + l];
        w |= (unsigned long long)(v >= 0.0f ? 1 : 0) << l;
    }
    wT[(size_t)j * NH + col] = w;
}

// ---------------------------------------------------------------------------
// GEMM1 replicating numpy einsum sum_of_products_contig_two (AVX512 npyv).
// Chain structure IDENTICAL to the 706us R9 kernel (bit-exact s1 output):
//   per (row,col): a[g][i] accumulates k = t*64 + g*16 + (jh*8+i), t = 0..11
//   ascending, tail k=768.. into group 0; combine (a0+a1)+(a2+a3); pair-sum
//   via shfl_xor(32); tree 8/4/2/1; BN f32 op-by-op; ballot -> sign bits.
// R16 = R14 + "#pragma unroll 1" on the t-loop. R14 post-mortem: VGPR hit the
// 128 cap exactly and spilled (WRITE_SIZE 18.9 GB scratch): the fully-unrolled
// t-loop (24 ds/FMA units per half) let the scheduler hoist loads across
// iterations, inflating live ranges past the cap. Loop-carried state = 64 accs
// + pointers (~75); per-iteration temps ~30 -> ~105 live < 128 once the
// hoist window is one t-iteration. g-offsets stay constant immediates.
// Structure vs R9 (math identical; R9 LDS GEOMETRY preserved exactly):
//   - wave = (rp, ch): rows {2rp, 2rp+1}, cols cb + ch*32 + colsub.
//     TWO rows per wave: w-frag read+unpacked ONCE per 16 MACs (was per 8)
//     -> VALU/MAC ~1.7 (was 2.25) and w-LDS bytes/MAC 1 (was 2; f32 weights
//     would be 4 B/MAC = ~750us LDS floor at 85 B/cyc/CU -> bf16 is right).
//   - w-read geometry = R9's proven-conflict-free: uint4 from row colsub
//     (+ch*32), pitch 204 words. x-reads wave-uniform broadcast (free).
//     [R12 post-mortem: lane-remap broke this -> 7.5e7 conflicts.]
//   - 64 accs as named arrays a0[4][8], a1[4][8], static indices only
//     (R11 post-mortem: pointer-select -> SROA failure -> scratch).
//   - __launch_bounds__(512,2) = CUDA min-BLOCKS semantics (measured:
//     (512,4)->cap 64 twice, (512,2)->cap 128).
//   - W staged bf16 for all 64 cols in two k-halves (t=0..5 | 6..11+tail,
//     ascending -> chain order unchanged). LDS 77,440 B -> 2 blocks/CU.
// Block: 512 thr = 8 waves; grid (NB/8, NH/64).
// ---------------------------------------------------------------------------
#define UNPACK_W(wA)                                                   \
    {                                                                  \
        unsigned int dw[4] = {wA.x, wA.y, wA.z, wA.w};                 \
        _Pragma("unroll")                                              \
        for (int p = 0; p < 4; ++p) {                                  \
            wf[2 * p]     = __uint_as_float(dw[p] << 16);              \
            wf[2 * p + 1] = __uint_as_float(dw[p] & 0xFFFF0000u);      \
        }                                                              \
    }

#define FMA8G(A, G, X0, X1)                                            \
    {                                                                  \
        float xv[8] = {X0.x, X0.y, X0.z, X0.w, X1.x, X1.y, X1.z, X1.w};\
        _Pragma("unroll")                                              \
        for (int i = 0; i < 8; ++i)                                    \
            A[G][i] = __fmaf_rn(wf[i], xv[i], A[G][i]);                \
    }

// combine + epilogue for one row; A = acc array NAME (static, no pointers)
#define COMB_EPI(A, RIDX)                                                    \
    {                                                                        \
        float v[8];                                                          \
        _Pragma("unroll")                                                    \
        for (int i = 0; i < 8; ++i)                                          \
            v[i] = __fadd_rn(__fadd_rn(A[0][i], A[1][i]),                    \
                             __fadd_rn(A[2][i], A[3][i]));                   \
        float h8[8];                                                         \
        _Pragma("unroll")                                                    \
        for (int i = 0; i < 8; ++i) {                                        \
            float o = __shfl_xor(v[i], 32, 64);                              \
            h8[i] = __fadd_rn(v[i], o);                                      \
        }                                                                    \
        float h4[4], h2[2];                                                  \
        _Pragma("unroll")                                                    \
        for (int i = 0; i < 4; ++i) h4[i] = __fadd_rn(h8[i], h8[i + 4]);     \
        _Pragma("unroll")                                                    \
        for (int i = 0; i < 2; ++i) h2[i] = __fadd_rn(h4[i], h4[i + 2]);     \
        float acc = __fadd_rn(h2[0], h2[1]);                                 \
        float h  = __fadd_rn(acc, bias);                                     \
        float t1 = __fsub_rn(h, mm);                                         \
        float u  = __fmul_rn(t1, sc);                                        \
        float hb = __fadd_rn(u, be);                                         \
        unsigned long long word = __ballot(hb >= 0.0f);                      \
        if (lane == 0)                                                       \
            s1p32[(size_t)(r0 + rA + (RIDX)) * (2 * NW) + blockIdx.y * 2 + ch] = \
                (unsigned int)word;                                          \
    }

__global__ __launch_bounds__(512, 2)
void k_gemm1_p2(const float* __restrict__ x, const unsigned short* __restrict__ wbf,
                const float* __restrict__ bnp, unsigned int* __restrict__ s1p32) {
    __shared__ alignas(16) float xs[8][XP];              // 25,216 B
    __shared__ alignas(16) unsigned short wl[64][WPB];   // 52,224 B

    const int tid = threadIdx.x;
    const int wave = tid >> 6, lane = tid & 63;
    const int colsub = lane & 31, jh = lane >> 5;
    const int j0 = jh * 8;
    const int rp = wave >> 1, ch = wave & 1;
    const int rA = 2 * rp;
    const int r0 = blockIdx.x * 8;
    const int cb = blockIdx.y * 64;

    // stage x: wave w stages block-row w (196 float4, lane-strided; reads occur
    // only after the first __syncthreads below)
    {
        const float4* src = (const float4*)(x + (size_t)(r0 + wave) * ND);
        float4* dst = (float4*)&xs[wave][0];
        for (int k4 = lane; k4 < ND / 4; k4 += 64) dst[k4] = src[k4];
    }

    float a0[4][8], a1[4][8];
#pragma unroll
    for (int g = 0; g < 4; ++g)
#pragma unroll
        for (int i = 0; i < 8; ++i) { a0[g][i] = 0.0f; a1[g][i] = 0.0f; }

    const float* xr0 = &xs[rA][j0];
    const float* xr1 = &xs[rA + 1][j0];
    const unsigned short* wrow = &wl[ch * 32 + colsub][j0];

#pragma unroll 1
    for (int half = 0; half < 2; ++half) {
        __syncthreads();   // half0: orders x-stage; half1: all waves done with wl half0
        // stage w half: 64 cols x (48|50) uint4 of bf16 signs; 8 threads/col
        // (48 uint4 = 384 bf16 = the 6 t-supertiles of this half; half1 +tail)
        {
            const int c = tid >> 3, q0 = tid & 7;
            const int nq = (half == 0) ? 48 : 50;    // half1: k 384..783 (400 bf16)
            uint4* dst = (uint4*)&wl[c][0];
            const uint4* src = (const uint4*)(wbf + (size_t)(cb + c) * ND) + half * 48;
            for (int q = q0; q < nq; q += 8) dst[q] = src[q];
        }
        __syncthreads();

        const int kb = half * 384;      // global k base of this half
#pragma unroll 1                        // R16: limit scheduler hoist window to one
                                        // t-iteration (R14 spilled at the 128 cap)
        for (int t = 0; t < 6; ++t) {   // global t = half*6 + t, ascending
#pragma unroll
            for (int g = 0; g < 4; ++g) {
                const int kk = t * 64 + g * 16;       // k offset within half
                uint4 wA = *(const uint4*)(wrow + kk);
                float wf[8];
                UNPACK_W(wA);
                float4 x0 = *(const float4*)(xr0 + kb + kk);
                float4 x1 = *(const float4*)(xr0 + kb + kk + 4);
                FMA8G(a0, g, x0, x1);
                float4 y0 = *(const float4*)(xr1 + kb + kk);
                float4 y1 = *(const float4*)(xr1 + kb + kk + 4);
                FMA8G(a1, g, y0, y1);
            }
        }
        if (half == 1) {
            // tail k = 768..783 (local 384..399) into group 0, after t=11
            uint4 wA = *(const uint4*)(wrow + 384);
            float wf[8];
            UNPACK_W(wA);
            float4 x0 = *(const float4*)(xr0 + 768);
            float4 x1 = *(const float4*)(xr0 + 768 + 4);
            FMA8G(a0, 0, x0, x1);
            float4 y0 = *(const float4*)(xr1 + 768);
            float4 y1 = *(const float4*)(xr1 + 768 + 4);
            FMA8G(a1, 0, y0, y1);
        }
    }

    // -------- combine + epilogue (exact R9 op sequence, per row) --------
    const int col = cb + ch * 32 + colsub;
    const float sc = bnp[col], mm = bnp[NH + col], be = bnp[2 * NH + col],
                bias = bnp[3 * NH + col];

    COMB_EPI(a0, 0)
    COMB_EPI(a1, 1)
}

// ---------------------------------------------------------------------------
// Binary layers 2/3: dot = 768 - 2*popcount(a XOR w) — exact integer, matches
// any-order f32 evaluation of +/-1 GEMM bit-for-bit (all partials exact).
// Epilogue faithful f32: h = fl(dot + b), BN op-by-op.
// MODE 0: sign -> packed bits. MODE 1: hardtanh -> f32 out.
// ---------------------------------------------------------------------------
template <int MODE>
__global__ __launch_bounds__(256, 2)
void k_popbin(const unsigned long long* __restrict__ Ap,
              const unsigned long long* __restrict__ wT,
              const float* __restrict__ bnp,
              unsigned long long* __restrict__ Sp, float* __restrict__ h_out) {
    __shared__ unsigned long long as[64][NW];
    const int tid = threadIdx.x;
    const int b0 = blockIdx.x * 64;

    {
        unsigned long long* asf = &as[0][0];
        const unsigned long long* src = Ap + (size_t)b0 * NW;
        for (int i = tid; i < 64 * NW; i += 256) asf[i] = src[i];
    }
    __syncthreads();

    const int wave = tid >> 6, lane = tid & 63;

    for (int chunk = 0; chunk < NW; ++chunk) {
        const int col = chunk * 64 + lane;
        unsigned long long w[NW];
#pragma unroll
        for (int j = 0; j < NW; ++j) w[j] = wT[(size_t)j * NH + col];
        const float sc = bnp[col], mm = bnp[NH + col], be = bnp[2 * NH + col],
                    bias = bnp[3 * NH + col];
        for (int r = 0; r < 16; ++r) {
            const int row = wave * 16 + r;
            int d = 0;
#pragma unroll
            for (int j = 0; j < NW; ++j)
                d += __builtin_popcountll(as[row][j] ^ w[j]);
            int dot = NH - 2 * d;
            float h  = __fadd_rn((float)dot, bias);
            float t  = __fsub_rn(h, mm);
            float u  = __fmul_rn(t, sc);
            float hb = __fadd_rn(u, be);
            if (MODE == 0) {
                unsigned long long word = __ballot(hb >= 0.0f);
                if (lane == 0) Sp[(size_t)(b0 + row) * NW + chunk] = word;
            } else {
                float hc = fminf(fmaxf(hb, -1.0f), 1.0f);
                h_out[(size_t)(b0 + row) * NH + col] = hc;
            }
        }
    }
}

// ---------------------------------------------------------------------------
// fc4 + log_softmax: one wave per row, double accumulation + shuffle reduce
// ---------------------------------------------------------------------------
__global__ __launch_bounds__(256, 4)
void k_fc4(const float* __restrict__ h3, const float* __restrict__ W4,
           const float* __restrict__ b4, float* __restrict__ out) {
    __shared__ float w4s[NC * NH];
    const int tid = threadIdx.x;
    for (int i = tid; i < NC * NH; i += 256) w4s[i] = W4[i];
    __syncthreads();

    const int wave = tid >> 6, lane = tid & 63;
    const int row = blockIdx.x * 4 + wave;
    const float* hrow = h3 + (size_t)row * NH;

    double p[NC];
#pragma unroll
    for (int c = 0; c < NC; ++c) p[c] = 0.0;

    for (int it = 0; it < NH / 64; ++it) {
        int j = it * 64 + lane;
        double hv = (double)hrow[j];
#pragma unroll
        for (int c = 0; c < NC; ++c) p[c] += hv * (double)w4s[c * NH + j];
    }
#pragma unroll
    for (int c = 0; c < NC; ++c) {
#pragma unroll
        for (int off = 32; off > 0; off >>= 1) p[c] += __shfl_xor(p[c], off, 64);
    }
    double lg[NC];
    double mx = -1e300;
#pragma unroll
    for (int c = 0; c < NC; ++c) {
        lg[c] = p[c] + (double)b4[c];
        mx = fmax(mx, lg[c]);
    }
    double s = 0.0;
#pragma unroll
    for (int c = 0; c < NC; ++c) s += exp(lg[c] - mx);
    double lse = mx + log(s);
    if (lane < NC) {
        double v = 0.0;
#pragma unroll
        for (int c = 0; c < NC; ++c)
            if (lane == c) v = lg[c];
        out[(size_t)row * NC + lane] = (float)(v - lse);
    }
}

// ---------------------------------------------------------------------------
// launch
// ---------------------------------------------------------------------------
extern "C" void kernel_launch(void* const* d_in, const int* in_sizes, int n_in,
                              void* d_out, int out_size, void* d_ws, size_t ws_size,
                              hipStream_t stream) {
    const float* x  = (const float*)d_in[0];
    const float* W1 = (const float*)d_in[1];
    const float* b1 = (const float*)d_in[2];
    const float* W2 = (const float*)d_in[3];
    const float* b2 = (const float*)d_in[4];
    const float* W3 = (const float*)d_in[5];
    const float* b3 = (const float*)d_in[6];
    const float* W4 = (const float*)d_in[7];
    const float* b4 = (const float*)d_in[8];
    const float* g1 = (const float*)d_in[9],  *be1 = (const float*)d_in[10];
    const float* m1 = (const float*)d_in[11], *v1  = (const float*)d_in[12];
    const float* g2 = (const float*)d_in[13], *be2 = (const float*)d_in[14];
    const float* m2 = (const float*)d_in[15], *v2  = (const float*)d_in[16];
    const float* g3 = (const float*)d_in[17], *be3 = (const float*)d_in[18];
    const float* m3 = (const float*)d_in[19], *v3  = (const float*)d_in[20];
    float* out = (float*)d_out;

    char* ws = (char*)d_ws;
    size_t off = 0;
    unsigned short* wbf = (unsigned short*)(ws + off);  off += (size_t)NH * ND * 2;
    unsigned long long* w2pT = (unsigned long long*)(ws + off); off += (size_t)NW * NH * 8;
    unsigned long long* w3pT = (unsigned long long*)(ws + off); off += (size_t)NW * NH * 8;
    unsigned long long* s1p  = (unsigned long long*)(ws + off); off += (size_t)NB * NW * 8;
    unsigned long long* s2p  = (unsigned long long*)(ws + off); off += (size_t)NB * NW * 8;
    float*  h3   = (float*)(ws + off);              off += (size_t)NB * NH * 4;
    float* bnp1 = (float*)(ws + off);               off += (size_t)4 * NH * 4;
    float* bnp2 = (float*)(ws + off);               off += (size_t)4 * NH * 4;
    float* bnp3 = (float*)(ws + off);               off += (size_t)4 * NH * 4;
    (void)ws_size; (void)in_sizes; (void)n_in; (void)out_size;

    // prep
    k_pack_w1bf<<<dim3(4, NH), 256, 0, stream>>>(W1, wbf);
    k_pack_wT<<<dim3((NH * NW + 255) / 256), 256, 0, stream>>>(W2, w2pT);
    k_pack_wT<<<dim3((NH * NW + 255) / 256), 256, 0, stream>>>(W3, w3pT);
    k_bnprep_f32<<<dim3(3), 256, 0, stream>>>(g1, be1, m1, v1, b1, bnp1);
    k_bnprep_f32<<<dim3(3), 256, 0, stream>>>(g2, be2, m2, v2, b2, bnp2);
    k_bnprep_f32<<<dim3(3), 256, 0, stream>>>(g3, be3, m3, v3, b3, bnp3);

    // layers
    k_gemm1_p2<<<dim3(NB / 8, NH / 64), 512, 0, stream>>>(x, wbf, bnp1,
                                                          (unsigned int*)s1p);
    k_popbin<0><<<dim3(NB / 64), 256, 0, stream>>>(s1p, w2pT, bnp2, s2p, nullptr);
    k_popbin<1><<<dim3(NB / 64), 256, 0, stream>>>(s2p, w3pT, bnp3, nullptr, h3);
    k_fc4<<<dim3(NB / 4), 256, 0, stream>>>(h3, W4, b4, out);
}

// Round 7
// 897.297 us; speedup vs baseline: 7.6270x; 1.1566x over previous
//
#include <hip/hip_runtime.h>
#include <hip/hip_fp16.h>
#include <math.h>
#include <stdint.h>

// Problem dims
#define NB 16384    // batch
#define NH 768      // hidden
#define ND 784      // input features
#define NC 10       // classes
#define NW 12       // u64 words per 768-bit row

// ---------------------------------------------------------------------------
// prep: BN params in FAITHFUL f32 (replicating np op-by-op):
// sc = g * (1 / sqrt(v + 1e-5)), each op f32-rounded. [0]=sc,[1]=m,[2]=be,[3]=bias
// ---------------------------------------------------------------------------
__global__ void k_bnprep_f32(const float* __restrict__ g, const float* __restrict__ be,
                             const float* __restrict__ m, const float* __restrict__ v,
                             const float* __restrict__ bias, float* __restrict__ out) {
    int i = blockIdx.x * 256 + threadIdx.x;
    if (i >= NH) return;
    float t1 = __fadd_rn(v[i], 1e-5f);
    float t2 = __fsqrt_rn(t1);
    float t3 = __fdiv_rn(1.0f, t2);
    out[i]          = __fmul_rn(g[i], t3);
    out[NH + i]     = m[i];
    out[2 * NH + i] = be[i];
    out[3 * NH + i] = bias[i];
}

// ---------------------------------------------------------------------------
// prep: W1 signs as f16 +/-1 bit patterns (0x3C00 / 0xBC00), row-major [col][k].
// f16 +/-1.0 converts EXACTLY to f32 +/-1.0 -> enables v_fma_mix_f32 (f32 FMA
// with f16 operand selected via op_sel) with bit-identical arithmetic.
// ---------------------------------------------------------------------------
__global__ void k_pack_w1h(const float* __restrict__ W1, unsigned short* __restrict__ wh) {
    int k = blockIdx.x * 256 + threadIdx.x;
    int col = blockIdx.y;
    if (k >= ND) return;
    float v = W1[(size_t)col * ND + k];
    wh[(size_t)col * ND + k] = (v >= 0.0f) ? (unsigned short)0x3C00 : (unsigned short)0xBC00;
}

// ---------------------------------------------------------------------------
// prep: W2/W3 sign bits, transposed words: wT[j*768 + col] bit l = (W[col][j*64+l] >= 0)
// ---------------------------------------------------------------------------
__global__ void k_pack_wT(const float* __restrict__ W, unsigned long long* __restrict__ wT) {
    int idx = blockIdx.x * 256 + threadIdx.x;
    if (idx >= NH * NW) return;
    int col = idx / NW, j = idx % NW;
    unsigned long long w = 0ull;
    for (int l = 0; l < 64; ++l) {
        float v = W[(size_t)col * NH + j * 64 + l];
        w |= (unsigned long long)(v >= 0.0f ? 1 : 0) << l;
    }
    wT[(size_t)j * NH + col] = w;
}

// ---------------------------------------------------------------------------
// GEMM1 replicating numpy einsum sum_of_products_contig_two (AVX512 npyv).
// R17 = the PROVEN R9 kernel (706us: VGPR 64, occ 45%, 0 bank conflicts,
// fully-unrolled t-loop = pipelined schedule) with ONE change: weights are
// f16 +/-1 and the product is written as __fmaf_rn(__low2float/__high2float
// (half2), x, acc). LLVM's mad-mix combine folds fma(fpext(f16),f32,f32)
// into v_fma_mix_f32 with op_sel -> the 8 unpack VALU ops per 8 MACs vanish
// (worst case: 8 v_cvt_f32_f16 = exact R9 instruction parity, no downside).
// f16->f32 is exact for +/-1 -> every FMA chain is bit-identical to R9.
// [R16 post-mortem: restructuring for fewer VALU/MAC (2 rows/wave) either
//  spilled at the 128 cap (full unroll) or serialized the loop (unroll 1,
//  VALUBusy 42%, occ 25%, 850us). Keep R9's schedule; delete instructions.]
// Thread = (row=wave, colsub=lane&31, jh=lane>>5): 32 accs, no spills.
// Chain order EXACT: a[g][i] accumulates k = t*64+g*16+(jh*8+i), t ascending,
// tail k=768.. into group 0, combine (a0+a1)+(a2+a3), tree 8/4/2/1
// (level-1 pair-sum via shfl_xor(32); IEEE add commutative -> bit-identical).
// Block: 512 thr = 8 waves; grid (NB/8, NH/64); LDS 76,800 B -> 2 blocks/CU.
// ---------------------------------------------------------------------------
__global__ __launch_bounds__(512, 4)
void k_gemm1_mx(const float* __restrict__ x, const unsigned short* __restrict__ wh16,
                const float* __restrict__ bnp,
                unsigned int* __restrict__ s1p32) {
    __shared__ float xs[8][ND];                         // 25,088 B
    __shared__ alignas(16) unsigned short wl[32][808];  // 51,712 B (pitch 1616 B)
    const int tid = threadIdx.x;
    const int r0 = blockIdx.x * 8;
    const int wave = tid >> 6, lane = tid & 63;
    const int colsub = lane & 31, jh = lane >> 5;
    const int j0 = jh * 8;

    // stage x: wave w stages its own row (196 float4); wave-coherent, no sync needed
    {
        const float4* src = (const float4*)(x + (size_t)(r0 + wave) * ND);
        float4* dst = (float4*)&xs[wave][0];
        for (int k4 = lane; k4 < 196; k4 += 64) dst[k4] = src[k4];
    }

    const float* xrow = &xs[wave][j0];

#pragma unroll 1
    for (int tile = 0; tile < 2; ++tile) {
        const int c0 = blockIdx.y * 64 + tile * 32;
        __syncthreads();   // tile1: all waves done reading wl tile0 (also orders tile0 stage)
        // stage w: 32 cols x 98 uint4 per col; 16 threads per col
        {
            int c = tid >> 4, q = tid & 15;
            uint4* dst = (uint4*)&wl[c][0];
            const uint4* srcp = (const uint4*)(wh16 + (size_t)(c0 + c) * ND);
#pragma unroll
            for (int k4 = q; k4 < 98; k4 += 16) dst[k4] = srcp[k4];
        }
        __syncthreads();

        const unsigned short* wrow = &wl[colsub][j0];

        float a[4][8];
#pragma unroll
        for (int g = 0; g < 4; ++g)
#pragma unroll
            for (int i = 0; i < 8; ++i) a[g][i] = 0.0f;

        // main loop: t = 0..11, each covers k = t*64 .. t*64+63
#pragma unroll
        for (int t = 0; t < 12; ++t) {
#pragma unroll
            for (int g = 0; g < 4; ++g) {
                const int kk = t * 64 + g * 16;
                uint4 wA = *(const uint4*)(wrow + kk);       // 8 f16: k = kk+j0 .. +7
                float4 x0 = *(const float4*)(xrow + kk);
                float4 x1 = *(const float4*)(xrow + kk + 4);
                unsigned int dw[4] = {wA.x, wA.y, wA.z, wA.w};
                float wf[8];
#pragma unroll
                for (int p = 0; p < 4; ++p) {
                    __half2 h2 = *reinterpret_cast<const __half2*>(&dw[p]);
                    wf[2 * p]     = __low2float(h2);   // folds into v_fma_mix op_sel lo
                    wf[2 * p + 1] = __high2float(h2);  // folds into v_fma_mix op_sel hi
                }
                float xv[8] = {x0.x, x0.y, x0.z, x0.w, x1.x, x1.y, x1.z, x1.w};
#pragma unroll
                for (int i = 0; i < 8; ++i)
                    a[g][i] = __fmaf_rn(wf[i], xv[i], a[g][i]);
            }
        }
        // single-vector tail: k = 768..783 into group 0
        {
            const int kk = 768;
            uint4 wA = *(const uint4*)(wrow + kk);
            float4 x0 = *(const float4*)(xrow + kk);
            float4 x1 = *(const float4*)(xrow + kk + 4);
            unsigned int dw[4] = {wA.x, wA.y, wA.z, wA.w};
            float wf[8];
#pragma unroll
            for (int p = 0; p < 4; ++p) {
                __half2 h2 = *reinterpret_cast<const __half2*>(&dw[p]);
                wf[2 * p]     = __low2float(h2);
                wf[2 * p + 1] = __high2float(h2);
            }
            float xv[8] = {x0.x, x0.y, x0.z, x0.w, x1.x, x1.y, x1.z, x1.w};
#pragma unroll
            for (int i = 0; i < 8; ++i)
                a[0][i] = __fmaf_rn(wf[i], xv[i], a[0][i]);
        }

        // combine: v[i] = (a0+a1)+(a2+a3) lane-wise (this thread's 8 j-lanes)
        float v[8];
#pragma unroll
        for (int i = 0; i < 8; ++i)
            v[i] = __fadd_rn(__fadd_rn(a[0][i], a[1][i]), __fadd_rn(a[2][i], a[3][i]));
        // tree level 1: h8[i] = v[i] + v[i+8]  (pair-exchange with jh-partner)
        float h8[8];
#pragma unroll
        for (int i = 0; i < 8; ++i) {
            float other = __shfl_xor(v[i], 32, 64);
            h8[i] = __fadd_rn(v[i], other);
        }
        // remaining tree: 4/2/1
        float h4[4], h2v[2];
#pragma unroll
        for (int i = 0; i < 4; ++i) h4[i] = __fadd_rn(h8[i], h8[i + 4]);
#pragma unroll
        for (int i = 0; i < 2; ++i) h2v[i] = __fadd_rn(h4[i], h4[i + 2]);
        float acc = __fadd_rn(h2v[0], h2v[1]);

        // epilogue: + b1, BN1 f32 op-by-op, sign -> packed bits (u32 half-word)
        const int col = c0 + colsub;
        const float sc = bnp[col], mm = bnp[NH + col], be = bnp[2 * NH + col],
                    bias = bnp[3 * NH + col];
        float h  = __fadd_rn(acc, bias);
        float t1 = __fsub_rn(h, mm);
        float u  = __fmul_rn(t1, sc);
        float hb = __fadd_rn(u, be);
        unsigned long long word = __ballot(hb >= 0.0f);   // bits 0..31 = cols (jh=0)
        if (lane == 0)
            s1p32[(size_t)(r0 + wave) * (2 * NW) + blockIdx.y * 2 + tile] =
                (unsigned int)word;
    }
}

// ---------------------------------------------------------------------------
// Binary layers 2/3: dot = 768 - 2*popcount(a XOR w) — exact integer, matches
// any-order f32 evaluation of +/-1 GEMM bit-for-bit (all partials exact).
// Epilogue faithful f32: h = fl(dot + b), BN op-by-op.
// MODE 0: sign -> packed bits. MODE 1: hardtanh -> f32 out.
// ---------------------------------------------------------------------------
template <int MODE>
__global__ __launch_bounds__(256, 2)
void k_popbin(const unsigned long long* __restrict__ Ap,
              const unsigned long long* __restrict__ wT,
              const float* __restrict__ bnp,
              unsigned long long* __restrict__ Sp, float* __restrict__ h_out) {
    __shared__ unsigned long long as[64][NW];
    const int tid = threadIdx.x;
    const int b0 = blockIdx.x * 64;

    {
        unsigned long long* asf = &as[0][0];
        const unsigned long long* src = Ap + (size_t)b0 * NW;
        for (int i = tid; i < 64 * NW; i += 256) asf[i] = src[i];
    }
    __syncthreads();

    const int wave = tid >> 6, lane = tid & 63;

    for (int chunk = 0; chunk < NW; ++chunk) {
        const int col = chunk * 64 + lane;
        unsigned long long w[NW];
#pragma unroll
        for (int j = 0; j < NW; ++j) w[j] = wT[(size_t)j * NH + col];
        const float sc = bnp[col], mm = bnp[NH + col], be = bnp[2 * NH + col],
                    bias = bnp[3 * NH + col];
        for (int r = 0; r < 16; ++r) {
            const int row = wave * 16 + r;
            int d = 0;
#pragma unroll
            for (int j = 0; j < NW; ++j)
                d += __builtin_popcountll(as[row][j] ^ w[j]);
            int dot = NH - 2 * d;
            float h  = __fadd_rn((float)dot, bias);
            float t  = __fsub_rn(h, mm);
            float u  = __fmul_rn(t, sc);
            float hb = __fadd_rn(u, be);
            if (MODE == 0) {
                unsigned long long word = __ballot(hb >= 0.0f);
                if (lane == 0) Sp[(size_t)(b0 + row) * NW + chunk] = word;
            } else {
                float hc = fminf(fmaxf(hb, -1.0f), 1.0f);
                h_out[(size_t)(b0 + row) * NH + col] = hc;
            }
        }
    }
}

// ---------------------------------------------------------------------------
// fc4 + log_softmax: one wave per row, double accumulation + shuffle reduce
// ---------------------------------------------------------------------------
__global__ __launch_bounds__(256, 4)
void k_fc4(const float* __restrict__ h3, const float* __restrict__ W4,
           const float* __restrict__ b4, float* __restrict__ out) {
    __shared__ float w4s[NC * NH];
    const int tid = threadIdx.x;
    for (int i = tid; i < NC * NH; i += 256) w4s[i] = W4[i];
    __syncthreads();

    const int wave = tid >> 6, lane = tid & 63;
    const int row = blockIdx.x * 4 + wave;
    const float* hrow = h3 + (size_t)row * NH;

    double p[NC];
#pragma unroll
    for (int c = 0; c < NC; ++c) p[c] = 0.0;

    for (int it = 0; it < NH / 64; ++it) {
        int j = it * 64 + lane;
        double hv = (double)hrow[j];
#pragma unroll
        for (int c = 0; c < NC; ++c) p[c] += hv * (double)w4s[c * NH + j];
    }
#pragma unroll
    for (int c = 0; c < NC; ++c) {
#pragma unroll
        for (int off = 32; off > 0; off >>= 1) p[c] += __shfl_xor(p[c], off, 64);
    }
    double lg[NC];
    double mx = -1e300;
#pragma unroll
    for (int c = 0; c < NC; ++c) {
        lg[c] = p[c] + (double)b4[c];
        mx = fmax(mx, lg[c]);
    }
    double s = 0.0;
#pragma unroll
    for (int c = 0; c < NC; ++c) s += exp(lg[c] - mx);
    double lse = mx + log(s);
    if (lane < NC) {
        double v = 0.0;
#pragma unroll
        for (int c = 0; c < NC; ++c)
            if (lane == c) v = lg[c];
        out[(size_t)row * NC + lane] = (float)(v - lse);
    }
}

// ---------------------------------------------------------------------------
// launch
// ---------------------------------------------------------------------------
extern "C" void kernel_launch(void* const* d_in, const int* in_sizes, int n_in,
                              void* d_out, int out_size, void* d_ws, size_t ws_size,
                              hipStream_t stream) {
    const float* x  = (const float*)d_in[0];
    const float* W1 = (const float*)d_in[1];
    const float* b1 = (const float*)d_in[2];
    const float* W2 = (const float*)d_in[3];
    const float* b2 = (const float*)d_in[4];
    const float* W3 = (const float*)d_in[5];
    const float* b3 = (const float*)d_in[6];
    const float* W4 = (const float*)d_in[7];
    const float* b4 = (const float*)d_in[8];
    const float* g1 = (const float*)d_in[9],  *be1 = (const float*)d_in[10];
    const float* m1 = (const float*)d_in[11], *v1  = (const float*)d_in[12];
    const float* g2 = (const float*)d_in[13], *be2 = (const float*)d_in[14];
    const float* m2 = (const float*)d_in[15], *v2  = (const float*)d_in[16];
    const float* g3 = (const float*)d_in[17], *be3 = (const float*)d_in[18];
    const float* m3 = (const float*)d_in[19], *v3  = (const float*)d_in[20];
    float* out = (float*)d_out;

    char* ws = (char*)d_ws;
    size_t off = 0;
    unsigned short* wh16 = (unsigned short*)(ws + off);  off += (size_t)NH * ND * 2;   // 1,204,224
    unsigned long long* w2pT = (unsigned long long*)(ws + off); off += (size_t)NW * NH * 8;  // 73,728
    unsigned long long* w3pT = (unsigned long long*)(ws + off); off += (size_t)NW * NH * 8;
    unsigned long long* s1p  = (unsigned long long*)(ws + off); off += (size_t)NB * NW * 8;  // 1,572,864
    unsigned long long* s2p  = (unsigned long long*)(ws + off); off += (size_t)NB * NW * 8;
    float*  h3   = (float*)(ws + off);              off += (size_t)NB * NH * 4;       // 50,331,648
    float* bnp1 = (float*)(ws + off);               off += (size_t)4 * NH * 4;
    float* bnp2 = (float*)(ws + off);               off += (size_t)4 * NH * 4;
    float* bnp3 = (float*)(ws + off);               off += (size_t)4 * NH * 4;
    (void)ws_size; (void)in_sizes; (void)n_in; (void)out_size;

    // prep
    k_pack_w1h<<<dim3(4, NH), 256, 0, stream>>>(W1, wh16);
    k_pack_wT<<<dim3((NH * NW + 255) / 256), 256, 0, stream>>>(W2, w2pT);
    k_pack_wT<<<dim3((NH * NW + 255) / 256), 256, 0, stream>>>(W3, w3pT);
    k_bnprep_f32<<<dim3(3), 256, 0, stream>>>(g1, be1, m1, v1, b1, bnp1);
    k_bnprep_f32<<<dim3(3), 256, 0, stream>>>(g2, be2, m2, v2, b2, bnp2);
    k_bnprep_f32<<<dim3(3), 256, 0, stream>>>(g3, be3, m3, v3, b3, bnp3);

    // layers
    k_gemm1_mx<<<dim3(NB / 8, NH / 64), 512, 0, stream>>>(x, wh16, bnp1,
                                                          (unsigned int*)s1p);
    k_popbin<0><<<dim3(NB / 64), 256, 0, stream>>>(s1p, w2pT, bnp2, s2p, nullptr);
    k_popbin<1><<<dim3(NB / 64), 256, 0, stream>>>(s2p, w3pT, bnp3, nullptr, h3);
    k_fc4<<<dim3(NB / 4), 256, 0, stream>>>(h3, W4, b4, out);
}